// Round 3
// baseline (630.433 us; speedup 1.0000x reference)
//
#include <hip/hip_runtime.h>
#include <hip/hip_cooperative_groups.h>

namespace cg = cooperative_groups;

// ---------------------------------------------------------------------------
// DeepFM forward, MI355X. Round 3: single cooperative mono-kernel.
// Phases (grid.sync between): [prep transposes + embed] -> gemm1+stats ->
// finstats1 -> gemm2(BN-fused A-stage)+stats -> finstats2 -> final.
// Fallback to 6 ordinary launches if cooperative launch fails.
// ---------------------------------------------------------------------------

#define B_ROWS 16384
#define VOCAB 100000
#define D0 640
#define H1 512
#define H2 256
#define EPSV 1e-5f

typedef short bf16x8 __attribute__((ext_vector_type(8)));
typedef float f32x4 __attribute__((ext_vector_type(4)));
typedef unsigned short u16;

struct Params {
    const int* Xi; const float* Xv; const float* bias;
    const float* dw1; const float* db1; const float* e1;
    const float* dw2; const float* db2; const float* e2;
    const float* W1; const float* g1; const float* bt1;
    const float* W2; const float* g2; const float* bt2;
    u16* so_bf; float* partial; u16* W1T; u16* W2T;
    float* psum1; float* psq1; float* psum2; float* psq2;
    float* a1; float* c1; float* a2; float* c2;
    u16* Z1bf; u16* Z2bf; float* out;
};

__device__ inline u16 f2bf(float x) {
    unsigned u = __float_as_uint(x);
    return (u16)((u + 0x7fffu + ((u >> 16) & 1u)) >> 16);   // RNE
}
__device__ inline float bf2f(unsigned b) {
    return __uint_as_float((b & 0xffffu) << 16);
}
__device__ inline void async16(const void* g, void* l) {
    __builtin_amdgcn_global_load_lds(
        (const __attribute__((address_space(1))) void*)g,
        (__attribute__((address_space(3))) void*)l, 16, 0, 0);
}

// ---------------------------------------------------------------------------
// P0: W1 (640x512 f32) -> W1T (512x640 bf16); W2 (512x256) -> W2T (256x512).
__device__ void phase_prep(const Params& p, char* smem) {
    float (*tile)[33] = (float (*)[33])smem;
    const int bid = blockIdx.x, tid = threadIdx.x;
    const float* W; u16* WT; int K, N, k0, n0;
    bool act = true;
    if (bid < 320)      { W = p.W1; WT = p.W1T; K = D0; N = H1; k0 = (bid % 20) * 32; n0 = (bid / 20) * 32; }
    else if (bid < 448) { int b2 = bid - 320; W = p.W2; WT = p.W2T; K = H1; N = H2; k0 = (b2 % 16) * 32; n0 = (b2 / 16) * 32; }
    else act = false;
    if (act) {
        int tx = tid & 31, ty4 = (tid >> 5) * 4;
#pragma unroll
        for (int r = 0; r < 4; ++r)
            tile[ty4 + r][tx] = W[(size_t)(k0 + ty4 + r) * N + n0 + tx];
        __syncthreads();
#pragma unroll
        for (int r = 0; r < 4; ++r)
            WT[(size_t)(n0 + ty4 + r) * K + k0 + tx] = f2bf(tile[tx][ty4 + r]);
    }
}

// ---------------------------------------------------------------------------
// P1: embed + FM (exact fp32). 64 lanes/row = 4 fgroups x 16 e. 8 passes.
__device__ void phase_embed(const Params& p) {
    const int tid = threadIdx.x;
    const int lane = tid & 63;
    const int wv = tid >> 6;
    const int e = lane & 15, fg = lane >> 4;
    for (int pass = 0; pass < 8; ++pass) {
        const int b = pass * 2048 + blockIdx.x * 4 + wv;
        const int* xr = p.Xi + (size_t)b * 40;
        const float* xvr = p.Xv + (size_t)b * 40;
        float accf = 0.f, s1 = 0.f, sq = 0.f;
#pragma unroll
        for (int j = 0; j < 4; ++j) {           // dense fields f = fg + 4j < 13
            int f = fg + 4 * j;
            bool live = f < 13;
            int ff = live ? f : 0;
            float x = (float)xr[ff];
            float xv = xvr[ff];
            float fo = (x * p.dw1[ff * 16 + e] + p.db1[ff * 16 + e]) * xv;
            float so = (x * p.dw2[ff * 16 + e] + p.db2[ff * 16 + e]) * xv;
            if (live) {
                accf += fo; s1 += so; sq += so * so;
                p.so_bf[(size_t)b * D0 + ff * 16 + e] = f2bf(so);
            }
        }
#pragma unroll
        for (int j = 0; j < 7; ++j) {           // sparse fields f = 13+fg+4j < 40
            int f = 13 + fg + 4 * j;
            bool live = f < 40;
            int ff = live ? f : 13;
            int idx = xr[ff];
            float xv = xvr[ff];
            size_t off = (size_t)(ff - 13) * VOCAB * 16 + (size_t)idx * 16 + e;
            float fo = p.e1[off] * xv;
            float so = p.e2[off] * xv;
            if (live) {
                accf += fo; s1 += so; sq += so * so;
                p.so_bf[(size_t)b * D0 + ff * 16 + e] = f2bf(so);
            }
        }
        // reduce over fgroups (same e): lanes differing in bits 4,5
        s1 += __shfl_xor(s1, 16);  s1 += __shfl_xor(s1, 32);
        sq += __shfl_xor(sq, 16);  sq += __shfl_xor(sq, 32);
        accf += __shfl_xor(accf, 16); accf += __shfl_xor(accf, 32);
        float val = accf + 0.5f * (s1 * s1 - sq);
        // reduce over e
        val += __shfl_xor(val, 1); val += __shfl_xor(val, 2);
        val += __shfl_xor(val, 4); val += __shfl_xor(val, 8);
        if (lane == 0) p.partial[b] = val + p.bias[b];
    }
}

// ---------------------------------------------------------------------------
// P2: Z1 = so @ W1^T(NT), 128x128 tile, BK=64, 2-phase dbuf, fused col stats.
__device__ void phase_gemm1(const Params& p, char* smem) {
    u16* As = (u16*)smem;                 // [2][128*64]
    u16* Bs = (u16*)(smem + 32768);       // [2][128*64]
    const int tid = threadIdx.x, lane = tid & 63, w = tid >> 6;
    const int m0 = (blockIdx.x >> 2) * 128, n0 = (blockIdx.x & 3) * 128;
    const int wr = w >> 1, wc = w & 1;
    const int srow = lane >> 3, scol = (lane & 7) * 8;

    f32x4 acc[4][4] = {};
    auto stage = [&](int buf, int kt) {
#pragma unroll
        for (int j = 0; j < 4; ++j) {
            int r0 = w * 32 + j * 8;
            async16(p.so_bf + (size_t)(m0 + r0 + srow) * D0 + kt + scol, As + buf * 8192 + r0 * 64);
            async16(p.W1T  + (size_t)(n0 + r0 + srow) * D0 + kt + scol, Bs + buf * 8192 + r0 * 64);
        }
    };
    stage(0, 0);
    __syncthreads();
    int cur = 0;
    for (int t = 0; t < 10; ++t) {
        if (t < 9) stage(cur ^ 1, (t + 1) * 64);
#pragma unroll
        for (int kk = 0; kk < 2; ++kk) {
            bf16x8 af[4], bfr[4];
#pragma unroll
            for (int i = 0; i < 4; ++i) {
                int ar = wr * 64 + i * 16 + (lane & 15);
                af[i] = *(const bf16x8*)&As[cur * 8192 + ar * 64 + kk * 32 + (lane >> 4) * 8];
                int br = wc * 64 + i * 16 + (lane & 15);
                bfr[i] = *(const bf16x8*)&Bs[cur * 8192 + br * 64 + kk * 32 + (lane >> 4) * 8];
            }
#pragma unroll
            for (int i = 0; i < 4; ++i)
#pragma unroll
                for (int j2 = 0; j2 < 4; ++j2)
                    acc[i][j2] = __builtin_amdgcn_mfma_f32_16x16x32_bf16(
                        af[i], bfr[j2], acc[i][j2], 0, 0, 0);
        }
        __syncthreads();
        cur ^= 1;
    }
#pragma unroll
    for (int i = 0; i < 4; ++i)
#pragma unroll
        for (int j2 = 0; j2 < 4; ++j2) {
            int row = m0 + wr * 64 + i * 16 + (lane >> 4) * 4;
            int col = n0 + wc * 64 + j2 * 16 + (lane & 15);
#pragma unroll
            for (int q = 0; q < 4; ++q)
                p.Z1bf[(size_t)(row + q) * H1 + col] = f2bf(acc[i][j2][q]);
        }
    const int chunk = (blockIdx.x >> 2) * 2 + wr;
#pragma unroll
    for (int j2 = 0; j2 < 4; ++j2) {
        float s = 0.f, q = 0.f;
#pragma unroll
        for (int i = 0; i < 4; ++i)
#pragma unroll
            for (int qq = 0; qq < 4; ++qq) { float v = acc[i][j2][qq]; s += v; q += v * v; }
        s += __shfl_xor(s, 16); s += __shfl_xor(s, 32);
        q += __shfl_xor(q, 16); q += __shfl_xor(q, 32);
        if (lane < 16) {
            int col = n0 + wc * 64 + j2 * 16 + lane;
            p.psum1[(size_t)chunk * H1 + col] = s;
            p.psq1[(size_t)chunk * H1 + col] = q;
        }
    }
}

// ---------------------------------------------------------------------------
__device__ void phase_finstats(const float* psum, const float* psq,
                               const float* g, const float* bt,
                               float* a, float* c, int N, int nblk) {
    if ((int)blockIdx.x < nblk) {
        int col = blockIdx.x * 256 + threadIdx.x;
        float s = 0.f, q = 0.f;
        for (int ch = 0; ch < 256; ++ch) {
            s += psum[(size_t)ch * N + col];
            q += psq[(size_t)ch * N + col];
        }
        const float inv = 1.0f / (float)B_ROWS;
        float mean = s * inv;
        float var = q * inv - mean * mean;
        float av = g[col] * rsqrtf(var + EPSV);
        a[col] = av;
        c[col] = bt[col] - mean * av;
    }
}

// ---------------------------------------------------------------------------
// P4: Z2 = BN1(Z1) @ W2^T(NT). 128x64 tile, BK=64, BN applied in A-staging
// (reg-stage Z1bf -> fma a1,c1 -> bf16 -> ds_write). Fused col stats.
__device__ void phase_gemm2(const Params& p, char* smem) {
    u16* As = (u16*)smem;                 // [2][128*64]
    u16* Bs = (u16*)(smem + 32768);       // [2][64*64]
    const int tid = threadIdx.x, lane = tid & 63, w = tid >> 6;
    const int m0 = (blockIdx.x >> 2) * 128, n0 = (blockIdx.x & 3) * 64;
    const int wr = w >> 1, wc = w & 1;

    f32x4 acc[4][2] = {};

    auto loadA = [&](uint4* zr, int kt) {
#pragma unroll
        for (int r = 0; r < 4; ++r) {
            int li = r * 256 + tid, row = li >> 3, c8 = (li & 7) * 8;
            zr[r] = *(const uint4*)(p.Z1bf + (size_t)(m0 + row) * H1 + kt + c8);
        }
    };
    auto writeA = [&](int buf, const uint4* zr, int kt) {
#pragma unroll
        for (int r = 0; r < 4; ++r) {
            int li = r * 256 + tid, row = li >> 3, c8 = (li & 7) * 8;
            float4 a0 = *(const float4*)(p.a1 + kt + c8);
            float4 a1v = *(const float4*)(p.a1 + kt + c8 + 4);
            float4 c0 = *(const float4*)(p.c1 + kt + c8);
            float4 c1v = *(const float4*)(p.c1 + kt + c8 + 4);
            uint4 z = zr[r];
            float f0 = bf2f(z.x), f1 = bf2f(z.x >> 16);
            float f2 = bf2f(z.y), f3 = bf2f(z.y >> 16);
            float f4 = bf2f(z.z), f5 = bf2f(z.z >> 16);
            float f6 = bf2f(z.w), f7 = bf2f(z.w >> 16);
            uint4 o;
            o.x = (unsigned)f2bf(f0 * a0.x + c0.x) | ((unsigned)f2bf(f1 * a0.y + c0.y) << 16);
            o.y = (unsigned)f2bf(f2 * a0.z + c0.z) | ((unsigned)f2bf(f3 * a0.w + c0.w) << 16);
            o.z = (unsigned)f2bf(f4 * a1v.x + c1v.x) | ((unsigned)f2bf(f5 * a1v.y + c1v.y) << 16);
            o.w = (unsigned)f2bf(f6 * a1v.z + c1v.z) | ((unsigned)f2bf(f7 * a1v.w + c1v.w) << 16);
            *(uint4*)(As + (size_t)buf * 8192 + row * 64 + c8) = o;
        }
    };
    auto stageB = [&](int buf, int kt) {
#pragma unroll
        for (int r = 0; r < 2; ++r) {
            int li = r * 256 + tid, row = li >> 3, c8 = (li & 7) * 8;
            async16(p.W2T + (size_t)(n0 + row) * H1 + kt + c8, Bs + buf * 4096 + row * 64 + c8);
        }
    };

    uint4 zr[4];
    loadA(zr, 0);
    stageB(0, 0);
    writeA(0, zr, 0);
    __syncthreads();
    int cur = 0;
    for (int t = 0; t < 8; ++t) {
        uint4 zn[4];
        if (t < 7) { loadA(zn, (t + 1) * 64); stageB(cur ^ 1, (t + 1) * 64); }
#pragma unroll
        for (int kk = 0; kk < 2; ++kk) {
            bf16x8 af[4], bfr[2];
#pragma unroll
            for (int i = 0; i < 4; ++i) {
                int ar = wr * 64 + i * 16 + (lane & 15);
                af[i] = *(const bf16x8*)&As[cur * 8192 + ar * 64 + kk * 32 + (lane >> 4) * 8];
            }
#pragma unroll
            for (int j2 = 0; j2 < 2; ++j2) {
                int br = wc * 32 + j2 * 16 + (lane & 15);
                bfr[j2] = *(const bf16x8*)&Bs[cur * 4096 + br * 64 + kk * 32 + (lane >> 4) * 8];
            }
#pragma unroll
            for (int i = 0; i < 4; ++i)
#pragma unroll
                for (int j2 = 0; j2 < 2; ++j2)
                    acc[i][j2] = __builtin_amdgcn_mfma_f32_16x16x32_bf16(
                        af[i], bfr[j2], acc[i][j2], 0, 0, 0);
        }
        if (t < 7) writeA(cur ^ 1, zn, (t + 1) * 64);
        __syncthreads();
        cur ^= 1;
    }
#pragma unroll
    for (int i = 0; i < 4; ++i)
#pragma unroll
        for (int j2 = 0; j2 < 2; ++j2) {
            int row = m0 + wr * 64 + i * 16 + (lane >> 4) * 4;
            int col = n0 + wc * 32 + j2 * 16 + (lane & 15);
#pragma unroll
            for (int q = 0; q < 4; ++q)
                p.Z2bf[(size_t)(row + q) * H2 + col] = f2bf(acc[i][j2][q]);
        }
    const int chunk = (blockIdx.x >> 2) * 2 + wr;
#pragma unroll
    for (int j2 = 0; j2 < 2; ++j2) {
        float s = 0.f, q = 0.f;
#pragma unroll
        for (int i = 0; i < 4; ++i)
#pragma unroll
            for (int qq = 0; qq < 4; ++qq) { float v = acc[i][j2][qq]; s += v; q += v * v; }
        s += __shfl_xor(s, 16); s += __shfl_xor(s, 32);
        q += __shfl_xor(q, 16); q += __shfl_xor(q, 32);
        if (lane < 16) {
            int col = n0 + wc * 32 + j2 * 16 + lane;
            p.psum2[(size_t)chunk * H2 + col] = s;
            p.psq2[(size_t)chunk * H2 + col] = q;
        }
    }
}

// ---------------------------------------------------------------------------
// P6: out[b] = partial[b] + sum_c (Z2[b,c]*a2[c] + c2[c]).
__device__ void phase_final(const Params& p) {
    const int wv = threadIdx.x >> 6, lane = threadIdx.x & 63;
    for (int pass = 0; pass < 8; ++pass) {
        int b = pass * 2048 + blockIdx.x * 4 + wv;
        ushort4 z4 = *(const ushort4*)(p.Z2bf + (size_t)b * H2 + lane * 4);
        float4 a = *(const float4*)(p.a2 + lane * 4);
        float4 c = *(const float4*)(p.c2 + lane * 4);
        float v = bf2f(z4.x) * a.x + c.x + bf2f(z4.y) * a.y + c.y
                + bf2f(z4.z) * a.z + c.z + bf2f(z4.w) * a.w + c.w;
#pragma unroll
        for (int m = 1; m < 64; m <<= 1) v += __shfl_xor(v, m);
        if (lane == 0) p.out[b] = p.partial[b] + v;
    }
}

// ---------------------------------------------------------------------------
__global__ __launch_bounds__(256, 2) void mono_k(Params p) {
    __shared__ __align__(16) char smem[65536];
    cg::grid_group grid = cg::this_grid();
    phase_prep(p, smem);
    phase_embed(p);
    __threadfence(); grid.sync();
    phase_gemm1(p, smem);
    __threadfence(); grid.sync();
    phase_finstats(p.psum1, p.psq1, p.g1, p.bt1, p.a1, p.c1, H1, 2);
    __threadfence(); grid.sync();
    phase_gemm2(p, smem);
    __threadfence(); grid.sync();
    phase_finstats(p.psum2, p.psq2, p.g2, p.bt2, p.a2, p.c2, H2, 1);
    __threadfence(); grid.sync();
    phase_final(p);
}

// Fallback (non-cooperative) path: same phases as separate kernels.
__global__ __launch_bounds__(256, 2) void k_p01(Params p) {
    __shared__ __align__(16) char smem[65536];
    phase_prep(p, smem); phase_embed(p);
}
__global__ __launch_bounds__(256, 2) void k_g1(Params p) {
    __shared__ __align__(16) char smem[65536];
    phase_gemm1(p, smem);
}
__global__ __launch_bounds__(256, 2) void k_f1(Params p) {
    phase_finstats(p.psum1, p.psq1, p.g1, p.bt1, p.a1, p.c1, H1, 2);
}
__global__ __launch_bounds__(256, 2) void k_g2(Params p) {
    __shared__ __align__(16) char smem[65536];
    phase_gemm2(p, smem);
}
__global__ __launch_bounds__(256, 2) void k_f2(Params p) {
    phase_finstats(p.psum2, p.psq2, p.g2, p.bt2, p.a2, p.c2, H2, 1);
}
__global__ __launch_bounds__(256, 2) void k_fin(Params p) {
    phase_final(p);
}

// ---------------------------------------------------------------------------
extern "C" void kernel_launch(void* const* d_in, const int* in_sizes, int n_in,
                              void* d_out, int out_size, void* d_ws, size_t ws_size,
                              hipStream_t stream)
{
    Params p;
    p.Xi   = (const int*)d_in[0];
    p.Xv   = (const float*)d_in[1];
    p.bias = (const float*)d_in[2];
    p.dw1  = (const float*)d_in[3];
    p.db1  = (const float*)d_in[4];
    p.e1   = (const float*)d_in[5];
    p.dw2  = (const float*)d_in[6];
    p.db2  = (const float*)d_in[7];
    p.e2   = (const float*)d_in[8];
    p.W1   = (const float*)d_in[9];
    // d_in[10] = b1: cancels in BN -> unused
    p.g1   = (const float*)d_in[11];
    p.bt1  = (const float*)d_in[12];
    p.W2   = (const float*)d_in[13];
    // d_in[14] = b2: cancels in BN -> unused
    p.g2   = (const float*)d_in[15];
    p.bt2  = (const float*)d_in[16];

    char* ws = (char*)d_ws;
    size_t off = 0;
    auto alloc = [&](size_t bytes) { char* q = ws + off; off += (bytes + 255) & ~(size_t)255; return q; };
    p.so_bf   = (u16*)alloc((size_t)B_ROWS * D0 * 2);
    p.partial = (float*)alloc((size_t)B_ROWS * 4);
    p.W1T     = (u16*)alloc((size_t)H1 * D0 * 2);
    p.W2T     = (u16*)alloc((size_t)H2 * H1 * 2);
    p.psum1   = (float*)alloc((size_t)256 * H1 * 4);
    p.psq1    = (float*)alloc((size_t)256 * H1 * 4);
    p.psum2   = (float*)alloc((size_t)256 * H2 * 4);
    p.psq2    = (float*)alloc((size_t)256 * H2 * 4);
    p.a1      = (float*)alloc(H1 * 4);
    p.c1      = (float*)alloc(H1 * 4);
    p.a2      = (float*)alloc(H2 * 4);
    p.c2      = (float*)alloc(H2 * 4);
    p.Z1bf    = (u16*)alloc((size_t)B_ROWS * H1 * 2);
    p.Z2bf    = (u16*)alloc((size_t)B_ROWS * H2 * 2);
    p.out     = (float*)d_out;
    (void)in_sizes; (void)n_in; (void)out_size; (void)ws_size;

    void* args[] = { &p };
    hipError_t err = hipLaunchCooperativeKernel((void*)mono_k, dim3(512), dim3(256),
                                                args, 0, stream);
    if (err != hipSuccess) {
        (void)hipGetLastError();   // clear, use fallback multi-kernel path
        k_p01<<<512, 256, 0, stream>>>(p);
        k_g1 <<<512, 256, 0, stream>>>(p);
        k_f1 <<<512, 256, 0, stream>>>(p);
        k_g2 <<<512, 256, 0, stream>>>(p);
        k_f2 <<<512, 256, 0, stream>>>(p);
        k_fin<<<512, 256, 0, stream>>>(p);
    }
}

// Round 4
// 101.524 us; speedup vs baseline: 6.2097x; 6.2097x over previous
//
#include <hip/hip_runtime.h>

// ---------------------------------------------------------------------------
// DeepFM forward, MI355X. Round 4: multi-kernel (grid.sync proved ~100us/sync
// on 8-XCD -> abandoned). BN1 folded into GEMM2 B-staging via algebra:
//   BN1(Z1)@W2 = Z1*diag(a1)*W2 + 1*(c1^T W2); rank-1 term is col-constant
//   and BN2 is invariant to col-constants -> dropped. No bn_apply, no D1, no c1.
// Kernels: embed_prep -> gemm1(+stats) -> finstats1(a1) ->
//          gemm2(B*=a1, +stats) -> finstats2(a2,c2) -> final.
// ---------------------------------------------------------------------------

#define B_ROWS 16384
#define VOCAB 100000
#define D0 640
#define H1 512
#define H2 256
#define EPSV 1e-5f

typedef short bf16x8 __attribute__((ext_vector_type(8)));
typedef float f32x4 __attribute__((ext_vector_type(4)));
typedef unsigned short u16;

struct Params {
    const int* Xi; const float* Xv; const float* bias;
    const float* dw1; const float* db1; const float* e1;
    const float* dw2; const float* db2; const float* e2;
    const float* W1; const float* g1; const float* bt1;
    const float* W2; const float* g2; const float* bt2;
    u16* so_bf; float* partial; u16* W1T; u16* W2T;
    float* psum1; float* psq1; float* psum2; float* psq2;
    float* a1; float* a2; float* c2;
    u16* Z1bf; u16* Z2bf; float* out;
};

__device__ inline u16 f2bf(float x) {
    unsigned u = __float_as_uint(x);
    return (u16)((u + 0x7fffu + ((u >> 16) & 1u)) >> 16);   // RNE
}
__device__ inline float bf2f(unsigned b) {
    return __uint_as_float((b & 0xffffu) << 16);
}
__device__ inline void async16(const void* g, void* l) {
    __builtin_amdgcn_global_load_lds(
        (const __attribute__((address_space(1))) void*)g,
        (__attribute__((address_space(3))) void*)l, 16, 0, 0);
}

// ---------------------------------------------------------------------------
// K1: fused weight transposes (blocks 0..447) + embed/FM (all 1024 blocks).
// Embed: 16 rows/block, 16 lanes/row; all 54 sparse gathers in flight.
__global__ __launch_bounds__(256) void embed_prep_k(Params p) {
    __shared__ float tile[32][33];
    const int bid = blockIdx.x, tid = threadIdx.x;

    if (bid < 448) {            // transpose W1 (320 tiles) / W2 (128 tiles)
        const float* W; u16* WT; int K, N, k0, n0;
        if (bid < 320) { W = p.W1; WT = p.W1T; K = D0; N = H1; k0 = (bid % 20) * 32; n0 = (bid / 20) * 32; }
        else { int b2 = bid - 320; W = p.W2; WT = p.W2T; K = H1; N = H2; k0 = (b2 % 16) * 32; n0 = (b2 / 16) * 32; }
        int tx = tid & 31, ty4 = (tid >> 5) * 4;
#pragma unroll
        for (int r = 0; r < 4; ++r)
            tile[ty4 + r][tx] = W[(size_t)(k0 + ty4 + r) * N + n0 + tx];
        __syncthreads();
#pragma unroll
        for (int r = 0; r < 4; ++r)
            WT[(size_t)(n0 + ty4 + r) * K + k0 + tx] = f2bf(tile[tx][ty4 + r]);
    }

    // ---- embed ----
    const int e = tid & 15;
    const int b = bid * 16 + (tid >> 4);
    const int* xr = p.Xi + (size_t)b * 40;
    const float* xvr = p.Xv + (size_t)b * 40;

    float accf = 0.f, s1 = 0.f, sq = 0.f;
#pragma unroll
    for (int f = 0; f < 13; ++f) {
        float x = (float)xr[f];
        float xv = xvr[f];
        float fo = (x * p.dw1[f * 16 + e] + p.db1[f * 16 + e]) * xv;
        float so = (x * p.dw2[f * 16 + e] + p.db2[f * 16 + e]) * xv;
        accf += fo; s1 += so; sq += so * so;
        p.so_bf[(size_t)b * D0 + f * 16 + e] = f2bf(so);
    }
    // hoist ALL sparse gathers (54 independent loads in flight)
    float v1[27], v2[27];
#pragma unroll
    for (int s = 0; s < 27; ++s) {
        size_t off = (size_t)s * (VOCAB * 16) + (size_t)xr[13 + s] * 16 + e;
        v1[s] = p.e1[off];
        v2[s] = p.e2[off];
    }
#pragma unroll
    for (int s = 0; s < 27; ++s) {
        float xv = xvr[13 + s];
        float fo = v1[s] * xv, so = v2[s] * xv;
        accf += fo; s1 += so; sq += so * so;
        p.so_bf[(size_t)b * D0 + (13 + s) * 16 + e] = f2bf(so);
    }
    float val = accf + 0.5f * (s1 * s1 - sq);
    val += __shfl_xor(val, 1); val += __shfl_xor(val, 2);
    val += __shfl_xor(val, 4); val += __shfl_xor(val, 8);
    if (e == 0) p.partial[b] = val + p.bias[b];
}

// ---------------------------------------------------------------------------
// K2: Z1 = so @ W1T^T (NT), 128x128 tile, BK=64, 2-phase dbuf, fused stats.
__global__ __launch_bounds__(256) void gemm1_k(Params p) {
    __shared__ u16 As[2][128 * 64];
    __shared__ u16 Bs[2][128 * 64];
    const int tid = threadIdx.x, lane = tid & 63, w = tid >> 6;
    const int m0 = ((int)blockIdx.x >> 2) * 128, n0 = ((int)blockIdx.x & 3) * 128;
    const int wr = w >> 1, wc = w & 1;
    const int srow = lane >> 3, scol = (lane & 7) * 8;

    f32x4 acc[4][4] = {};
    auto stage = [&](int buf, int kt) {
#pragma unroll
        for (int j = 0; j < 4; ++j) {
            int r0 = w * 32 + j * 8;
            async16(p.so_bf + (size_t)(m0 + r0 + srow) * D0 + kt + scol, &As[buf][r0 * 64]);
            async16(p.W1T  + (size_t)(n0 + r0 + srow) * D0 + kt + scol, &Bs[buf][r0 * 64]);
        }
    };
    stage(0, 0);
    __syncthreads();
    int cur = 0;
    for (int t = 0; t < 10; ++t) {
        if (t < 9) stage(cur ^ 1, (t + 1) * 64);
#pragma unroll
        for (int kk = 0; kk < 2; ++kk) {
            bf16x8 af[4], bfr[4];
#pragma unroll
            for (int i = 0; i < 4; ++i) {
                int ar = wr * 64 + i * 16 + (lane & 15);
                af[i] = *(const bf16x8*)&As[cur][ar * 64 + kk * 32 + (lane >> 4) * 8];
                int br = wc * 64 + i * 16 + (lane & 15);
                bfr[i] = *(const bf16x8*)&Bs[cur][br * 64 + kk * 32 + (lane >> 4) * 8];
            }
#pragma unroll
            for (int i = 0; i < 4; ++i)
#pragma unroll
                for (int j2 = 0; j2 < 4; ++j2)
                    acc[i][j2] = __builtin_amdgcn_mfma_f32_16x16x32_bf16(
                        af[i], bfr[j2], acc[i][j2], 0, 0, 0);
        }
        __syncthreads();
        cur ^= 1;
    }
#pragma unroll
    for (int i = 0; i < 4; ++i)
#pragma unroll
        for (int j2 = 0; j2 < 4; ++j2) {
            int row = m0 + wr * 64 + i * 16 + (lane >> 4) * 4;
            int col = n0 + wc * 64 + j2 * 16 + (lane & 15);
#pragma unroll
            for (int q = 0; q < 4; ++q)
                p.Z1bf[(size_t)(row + q) * H1 + col] = f2bf(acc[i][j2][q]);
        }
    const int chunk = ((int)blockIdx.x >> 2) * 2 + wr;
#pragma unroll
    for (int j2 = 0; j2 < 4; ++j2) {
        float s = 0.f, q = 0.f;
#pragma unroll
        for (int i = 0; i < 4; ++i)
#pragma unroll
            for (int qq = 0; qq < 4; ++qq) { float v = acc[i][j2][qq]; s += v; q += v * v; }
        s += __shfl_xor(s, 16); s += __shfl_xor(s, 32);
        q += __shfl_xor(q, 16); q += __shfl_xor(q, 32);
        if (lane < 16) {
            int col = n0 + wc * 64 + j2 * 16 + lane;
            p.psum1[(size_t)chunk * H1 + col] = s;
            p.psq1[(size_t)chunk * H1 + col] = q;
        }
    }
}

// ---------------------------------------------------------------------------
// K3: a1[col] = g1 * rsqrt(var+eps). (c1 not needed: BN2 col-const invariance.)
__global__ __launch_bounds__(256) void finstats1_k(Params p) {
    int col = blockIdx.x * 256 + threadIdx.x;
    float s = 0.f, q = 0.f;
    for (int ch = 0; ch < 256; ++ch) {
        s += p.psum1[(size_t)ch * H1 + col];
        q += p.psq1[(size_t)ch * H1 + col];
    }
    const float inv = 1.0f / (float)B_ROWS;
    float mean = s * inv;
    float var = q * inv - mean * mean;
    p.a1[col] = p.g1[col] * rsqrtf(var + EPSV);
}

// ---------------------------------------------------------------------------
// K4: Z2 = Z1 * diag(a1) * W2  (a1 folded into reg-staged B). 128x64 tile.
__global__ __launch_bounds__(256) void gemm2_k(Params p) {
    __shared__ u16 As[2][128 * 64];
    __shared__ u16 Bs[2][64 * 64];
    const int tid = threadIdx.x, lane = tid & 63, w = tid >> 6;
    const int m0 = ((int)blockIdx.x >> 2) * 128, n0 = ((int)blockIdx.x & 3) * 64;
    const int wr = w >> 1, wc = w & 1;
    const int srow = lane >> 3, scol = (lane & 7) * 8;

    f32x4 acc[4][2] = {};

    auto stageA = [&](int buf, int kt) {
#pragma unroll
        for (int j = 0; j < 4; ++j) {
            int r0 = w * 32 + j * 8;
            async16(p.Z1bf + (size_t)(m0 + r0 + srow) * H1 + kt + scol, &As[buf][r0 * 64]);
        }
    };
    auto loadB = [&](uint4* br, int kt) {
#pragma unroll
        for (int r = 0; r < 2; ++r) {
            int li = r * 256 + tid, row = li >> 3, c8 = (li & 7) * 8;
            br[r] = *(const uint4*)(p.W2T + (size_t)(n0 + row) * H1 + kt + c8);
        }
    };
    auto writeB = [&](int buf, const uint4* br, int kt) {
#pragma unroll
        for (int r = 0; r < 2; ++r) {
            int li = r * 256 + tid, row = li >> 3, c8 = (li & 7) * 8;
            float4 alo = *(const float4*)(p.a1 + kt + c8);
            float4 ahi = *(const float4*)(p.a1 + kt + c8 + 4);
            uint4 z = br[r];
            uint4 o;
            o.x = (unsigned)f2bf(bf2f(z.x) * alo.x) | ((unsigned)f2bf(bf2f(z.x >> 16) * alo.y) << 16);
            o.y = (unsigned)f2bf(bf2f(z.y) * alo.z) | ((unsigned)f2bf(bf2f(z.y >> 16) * alo.w) << 16);
            o.z = (unsigned)f2bf(bf2f(z.z) * ahi.x) | ((unsigned)f2bf(bf2f(z.z >> 16) * ahi.y) << 16);
            o.w = (unsigned)f2bf(bf2f(z.w) * ahi.z) | ((unsigned)f2bf(bf2f(z.w >> 16) * ahi.w) << 16);
            *(uint4*)&Bs[buf][row * 64 + c8] = o;
        }
    };

    uint4 breg[2];
    stageA(0, 0);
    loadB(breg, 0);
    writeB(0, breg, 0);
    __syncthreads();
    int cur = 0;
    for (int t = 0; t < 8; ++t) {
        uint4 bnx[2];
        if (t < 7) { stageA(cur ^ 1, (t + 1) * 64); loadB(bnx, (t + 1) * 64); }
#pragma unroll
        for (int kk = 0; kk < 2; ++kk) {
            bf16x8 af[4], bfr[2];
#pragma unroll
            for (int i = 0; i < 4; ++i) {
                int ar = wr * 64 + i * 16 + (lane & 15);
                af[i] = *(const bf16x8*)&As[cur][ar * 64 + kk * 32 + (lane >> 4) * 8];
            }
#pragma unroll
            for (int j2 = 0; j2 < 2; ++j2) {
                int br = wc * 32 + j2 * 16 + (lane & 15);
                bfr[j2] = *(const bf16x8*)&Bs[cur][br * 64 + kk * 32 + (lane >> 4) * 8];
            }
#pragma unroll
            for (int i = 0; i < 4; ++i)
#pragma unroll
                for (int j2 = 0; j2 < 2; ++j2)
                    acc[i][j2] = __builtin_amdgcn_mfma_f32_16x16x32_bf16(
                        af[i], bfr[j2], acc[i][j2], 0, 0, 0);
        }
        if (t < 7) writeB(cur ^ 1, bnx, (t + 1) * 64);
        __syncthreads();
        cur ^= 1;
    }
#pragma unroll
    for (int i = 0; i < 4; ++i)
#pragma unroll
        for (int j2 = 0; j2 < 2; ++j2) {
            int row = m0 + wr * 64 + i * 16 + (lane >> 4) * 4;
            int col = n0 + wc * 32 + j2 * 16 + (lane & 15);
#pragma unroll
            for (int q = 0; q < 4; ++q)
                p.Z2bf[(size_t)(row + q) * H2 + col] = f2bf(acc[i][j2][q]);
        }
    const int chunk = ((int)blockIdx.x >> 2) * 2 + wr;
#pragma unroll
    for (int j2 = 0; j2 < 2; ++j2) {
        float s = 0.f, q = 0.f;
#pragma unroll
        for (int i = 0; i < 4; ++i)
#pragma unroll
            for (int qq = 0; qq < 4; ++qq) { float v = acc[i][j2][qq]; s += v; q += v * v; }
        s += __shfl_xor(s, 16); s += __shfl_xor(s, 32);
        q += __shfl_xor(q, 16); q += __shfl_xor(q, 32);
        if (lane < 16) {
            int col = n0 + wc * 32 + j2 * 16 + lane;
            p.psum2[(size_t)chunk * H2 + col] = s;
            p.psq2[(size_t)chunk * H2 + col] = q;
        }
    }
}

// ---------------------------------------------------------------------------
// K5: a2,c2 from psum2/psq2.
__global__ __launch_bounds__(256) void finstats2_k(Params p) {
    int col = threadIdx.x;
    float s = 0.f, q = 0.f;
    for (int ch = 0; ch < 256; ++ch) {
        s += p.psum2[(size_t)ch * H2 + col];
        q += p.psq2[(size_t)ch * H2 + col];
    }
    const float inv = 1.0f / (float)B_ROWS;
    float mean = s * inv;
    float var = q * inv - mean * mean;
    float av = p.g2[col] * rsqrtf(var + EPSV);
    p.a2[col] = av;
    p.c2[col] = p.bt2[col] - mean * av;
}

// ---------------------------------------------------------------------------
// K6: out[b] = partial[b] + sum_c (Z2[b,c]*a2[c] + c2[c]).
__global__ __launch_bounds__(256) void final_k(Params p) {
    int w = threadIdx.x >> 6, lane = threadIdx.x & 63;
    int b = blockIdx.x * 4 + w;
    ushort4 z4 = *(const ushort4*)(p.Z2bf + (size_t)b * H2 + lane * 4);
    float4 a = *(const float4*)(p.a2 + lane * 4);
    float4 c = *(const float4*)(p.c2 + lane * 4);
    float v = bf2f(z4.x) * a.x + c.x + bf2f(z4.y) * a.y + c.y
            + bf2f(z4.z) * a.z + c.z + bf2f(z4.w) * a.w + c.w;
#pragma unroll
    for (int m = 1; m < 64; m <<= 1) v += __shfl_xor(v, m);
    if (lane == 0) p.out[b] = p.partial[b] + v;
}

// ---------------------------------------------------------------------------
extern "C" void kernel_launch(void* const* d_in, const int* in_sizes, int n_in,
                              void* d_out, int out_size, void* d_ws, size_t ws_size,
                              hipStream_t stream)
{
    Params p;
    p.Xi   = (const int*)d_in[0];
    p.Xv   = (const float*)d_in[1];
    p.bias = (const float*)d_in[2];
    p.dw1  = (const float*)d_in[3];
    p.db1  = (const float*)d_in[4];
    p.e1   = (const float*)d_in[5];
    p.dw2  = (const float*)d_in[6];
    p.db2  = (const float*)d_in[7];
    p.e2   = (const float*)d_in[8];
    p.W1   = (const float*)d_in[9];
    // d_in[10] = b1: cancels in BN1 -> unused
    p.g1   = (const float*)d_in[11];
    p.bt1  = (const float*)d_in[12];   // shifts BN1 output by col-const -> cancels in BN2 -> unused
    p.W2   = (const float*)d_in[13];
    // d_in[14] = b2: cancels in BN2 -> unused
    p.g2   = (const float*)d_in[15];
    p.bt2  = (const float*)d_in[16];

    char* ws = (char*)d_ws;
    size_t off = 0;
    auto alloc = [&](size_t bytes) { char* q = ws + off; off += (bytes + 255) & ~(size_t)255; return q; };
    p.so_bf   = (u16*)alloc((size_t)B_ROWS * D0 * 2);
    p.partial = (float*)alloc((size_t)B_ROWS * 4);
    p.W1T     = (u16*)alloc((size_t)H1 * D0 * 2);
    p.W2T     = (u16*)alloc((size_t)H2 * H1 * 2);
    p.psum1   = (float*)alloc((size_t)256 * H1 * 4);
    p.psq1    = (float*)alloc((size_t)256 * H1 * 4);
    p.psum2   = (float*)alloc((size_t)256 * H2 * 4);
    p.psq2    = (float*)alloc((size_t)256 * H2 * 4);
    p.a1      = (float*)alloc(H1 * 4);
    p.a2      = (float*)alloc(H2 * 4);
    p.c2      = (float*)alloc(H2 * 4);
    p.Z1bf    = (u16*)alloc((size_t)B_ROWS * H1 * 2);
    p.Z2bf    = (u16*)alloc((size_t)B_ROWS * H2 * 2);
    p.out     = (float*)d_out;
    (void)in_sizes; (void)n_in; (void)out_size; (void)ws_size;

    embed_prep_k<<<1024, 256, 0, stream>>>(p);
    gemm1_k    <<<512, 256, 0, stream>>>(p);
    finstats1_k<<<2, 256, 0, stream>>>(p);
    gemm2_k    <<<512, 256, 0, stream>>>(p);
    finstats2_k<<<1, 256, 0, stream>>>(p);
    final_k    <<<B_ROWS / 4, 256, 0, stream>>>(p);
}